// Round 4
// baseline (1188.779 us; speedup 1.0000x reference)
//
#include <hip/hip_runtime.h>
#include <hip/hip_bf16.h>
#include <cstdint>

// Problem constants
#define BB 4096
#define FF 2048
#define HD 2048           // H*D = 16*128
#define PROJ_N 2730
#define UPN 5460          // 2*PROJ
#define PROJ_PAD 2816     // 176*16 (pair-padded PROJ; also down-GEMM K: 44*64)
#define UPN_PAIR 5632     // 2*PROJ_PAD = 22*256 n-blocks for up GEMM

typedef __attribute__((ext_vector_type(8))) short bf16x8;
typedef __attribute__((ext_vector_type(4))) float f32x4;

__device__ __forceinline__ unsigned short f2bf(float f) {
  union { float f; unsigned int u; } x; x.f = f;
  unsigned int r = x.u + 0x7fffu + ((x.u >> 16) & 1u);
  return (unsigned short)(r >> 16);
}

// ---------------------------------------------------------------------------
// Kernel 1: LayerNorm + x_prev shift + n-all-zero flag
// ---------------------------------------------------------------------------
__global__ __launch_bounds__(256) void ln_prep(
    const float* __restrict__ inputs, const float* __restrict__ x_prev,
    const float* __restrict__ n_state,
    const float* __restrict__ ln_scale, const float* __restrict__ ln_bias,
    unsigned short* __restrict__ x_t_bf, float* __restrict__ xprev_out,
    int* __restrict__ flags)
{
  int b = blockIdx.x, t = threadIdx.x;
  const float* row = inputs + ((long)b << 11);
  float x[8];
  {
    float4 a = *(const float4*)(row + t * 8);
    float4 c = *(const float4*)(row + t * 8 + 4);
    x[0]=a.x; x[1]=a.y; x[2]=a.z; x[3]=a.w; x[4]=c.x; x[5]=c.y; x[6]=c.z; x[7]=c.w;
  }
  float s = 0.f, sq = 0.f;
#pragma unroll
  for (int k = 0; k < 8; ++k) { s += x[k]; sq += x[k] * x[k]; }

  const float* nrow = n_state + ((long)b << 11);
  int nz;
  {
    float4 a = *(const float4*)(nrow + t * 8);
    float4 c = *(const float4*)(nrow + t * 8 + 4);
    nz = (a.x != 0.f) | (a.y != 0.f) | (a.z != 0.f) | (a.w != 0.f) |
         (c.x != 0.f) | (c.y != 0.f) | (c.z != 0.f) | (c.w != 0.f);
  }

#pragma unroll
  for (int off = 32; off >= 1; off >>= 1) {
    s  += __shfl_xor(s, off);
    sq += __shfl_xor(sq, off);
  }
  __shared__ float ws_s[4], ws_q[4];
  __shared__ int s_nz;
  if (t == 0) s_nz = 0;
  __syncthreads();
  if (nz) s_nz = 1;                       // benign race, same value
  int wave = t >> 6;
  if ((t & 63) == 0) { ws_s[wave] = s; ws_q[wave] = sq; }
  __syncthreads();
  float ts = ws_s[0] + ws_s[1] + ws_s[2] + ws_s[3];
  float tq = ws_q[0] + ws_q[1] + ws_q[2] + ws_q[3];
  float mu  = ts * (1.f / 2048.f);
  float var = tq * (1.f / 2048.f) - mu * mu;
  float rs  = rsqrtf(var + 2048.0f);      // LN_EPS = float(F) = 2048

  unsigned short outb[8];
  float y[8];
#pragma unroll
  for (int k = 0; k < 8; ++k) {
    int c = t * 8 + k;
    float v = (x[k] - mu) * rs * ln_scale[c] + ln_bias[c];
    y[k] = v;
    outb[k] = f2bf(v);
  }
  *(uint4*)&x_t_bf[((long)b << 11) + t * 8] = *(uint4*)outb;
  float* xo = xprev_out + (long)b * 6144 + 4096 + t * 8;
  *(float4*)(xo)     = make_float4(y[0], y[1], y[2], y[3]);
  *(float4*)(xo + 4) = make_float4(y[4], y[5], y[6], y[7]);
  const float* src = x_prev + (long)b * 6144 + 2048;
  float* dst = xprev_out + (long)b * 6144;
  for (int i = t; i < 1024; i += 256)
    *(float4*)(dst + i * 4) = *(const float4*)(src + i * 4);
  if (t == 0) flags[b] = (s_nz == 0) ? 1 : 0;
}

// ---------------------------------------------------------------------------
// Kernel 2: transpose + cast fp32 (R x C) -> bf16 (OC x OK), zero padded.
// ---------------------------------------------------------------------------
__global__ __launch_bounds__(256) void transpose_cast(
    const float* __restrict__ in, unsigned short* __restrict__ out,
    int R, int C, int OC, int OK)
{
  __shared__ float tile[32][33];
  int ro0 = blockIdx.x * 32;
  int co0 = blockIdx.y * 32;
  int tx = threadIdx.x & 31, ty = threadIdx.x >> 5;
#pragma unroll
  for (int i = 0; i < 4; ++i) {
    int r = ro0 + ty + i * 8, cc = co0 + tx;
    float v = (r < R && cc < C) ? in[(long)r * C + cc] : 0.f;
    tile[ty + i * 8][tx] = v;
  }
  __syncthreads();
#pragma unroll
  for (int i = 0; i < 4; ++i) {
    int oc = co0 + ty + i * 8, ok = ro0 + tx;
    if (oc < OC && ok < OK)
      out[(long)oc * OK + ok] = f2bf(tile[tx][ty + i * 8]);
  }
}

// ---------------------------------------------------------------------------
// Kernel 2b: transpose + cast up_k (2048 x 5460) -> upT (5632 x 2048),
// PAIR-INTERLEAVED rows: logical o1 col p (<2730) -> row (p>>4)*32 + (p&15);
// logical o2 col (2730+p) -> row (p>>4)*32 + 16 + (p&15).  So each 256-row
// n-block of upT holds 8 pair-groups of [16 o1 | 16 o2] — the up GEMM's
// epilogue then finds o1 (even 16-frag) and matching o2 (odd 16-frag) in the
// SAME lane/rows and fuses o1*gelu(o2) in-register.  Rows never written
// (p>=2730 pads) keep workspace poison (NaN) — col-isolated by MFMA and
// overwritten with 0 by the epilogue's p<2730 guard.
// ---------------------------------------------------------------------------
__global__ __launch_bounds__(256) void transpose_cast_pair(
    const float* __restrict__ in, unsigned short* __restrict__ out)
{
  __shared__ float tile[32][33];
  int ro0 = blockIdx.x * 32;   // input-row (K) base, K=2048 exact
  int co0 = blockIdx.y * 32;   // input-col base over 5460
  int tx = threadIdx.x & 31, ty = threadIdx.x >> 5;
#pragma unroll
  for (int i = 0; i < 4; ++i) {
    int r = ro0 + ty + i * 8, cc = co0 + tx;
    float v = (cc < UPN) ? in[(long)r * UPN + cc] : 0.f;
    tile[ty + i * 8][tx] = v;
  }
  __syncthreads();
#pragma unroll
  for (int i = 0; i < 4; ++i) {
    int oc = co0 + ty + i * 8, ok = ro0 + tx;
    if (oc < UPN) {
      int pos = (oc < PROJ_N)
        ? ((oc >> 4) * 32 + (oc & 15))
        : (((oc - PROJ_N) >> 4) * 32 + 16 + ((oc - PROJ_N) & 15));
      out[(long)pos * 2048 + ok] = f2bf(tile[tx][ty + i * 8]);
    }
  }
}

// ---------------------------------------------------------------------------
// Kernel 3: 256x256 8-phase NT bf16 MFMA GEMM (m201-class schedule),
//           2-tiles-ahead prefetch.  See round-3 comments for the schedule,
//   swizzle, and region-lifetime proofs (unchanged).
//   NEW: gmode=1 epilogue fuses o1*gelu(o2) for the pair-interleaved up GEMM
//   and writes bf16 Hg[gm][p] (ld PROJ_PAD) directly; gmode=0 is the normal
//   fp32 C write (+bias +resid).
// ---------------------------------------------------------------------------
#define P_PRE()  do { __builtin_amdgcn_s_barrier(); \
                      asm volatile("s_waitcnt lgkmcnt(0)" ::: "memory"); \
                      __builtin_amdgcn_sched_barrier(0); \
                      __builtin_amdgcn_s_setprio(1); } while (0)
#define P_POST() do { __builtin_amdgcn_s_setprio(0); \
                      __builtin_amdgcn_sched_barrier(0); \
                      __builtin_amdgcn_s_barrier(); \
                      __builtin_amdgcn_sched_barrier(0); } while (0)

#define STAGE_A(h, k2, bo, kt)                                               \
  __builtin_amdgcn_global_load_lds(                                          \
      (const __attribute__((address_space(1))) void*)(pA[h][k2] + (long)(kt)*64), \
      (__attribute__((address_space(3))) void*)(ldsA + (bo) + ((k2)*16384 + (h)*8192) + wvu*1024), \
      16, 0, 0)
#define STAGE_B(cb, i, bo, kt)                                               \
  __builtin_amdgcn_global_load_lds(                                          \
      (const __attribute__((address_space(1))) void*)(pB[cb][i] + (long)(kt)*64), \
      (__attribute__((address_space(3))) void*)(ldsB + (bo) + ((cb)*16384 + (i)*8192) + wvu*1024), \
      16, 0, 0)

#define LOAD_A(rb, bo)                                                       \
  { _Pragma("unroll")                                                        \
    for (int f = 0; f < 4; ++f) {                                            \
      const char* p_ = ldsA + (bo) + (unsigned)((wm*128 + (rb)*64 + f*16 + m16) << 7); \
      aF[f][0] = *(const bf16x8*)(p_ + s0);                                  \
      aF[f][1] = *(const bf16x8*)(p_ + s1);                                  \
    } }
#define LOAD_B(cb, BV, bo)                                                   \
  { _Pragma("unroll")                                                        \
    for (int f = 0; f < 2; ++f) {                                            \
      const char* p_ = ldsB + (bo) + (unsigned)(((cb)*128 + wn*32 + f*16 + m16) << 7); \
      BV[f][0] = *(const bf16x8*)(p_ + s0);                                  \
      BV[f][1] = *(const bf16x8*)(p_ + s1);                                  \
    } }
#define MFMA_PH(rb, cb, BV)                                                  \
  { _Pragma("unroll")                                                        \
    for (int f = 0; f < 4; ++f) {                                            \
      acc[(rb)*4+f][(cb)*2+0] = __builtin_amdgcn_mfma_f32_16x16x32_bf16(     \
          aF[f][0], BV[0][0], acc[(rb)*4+f][(cb)*2+0], 0, 0, 0);             \
      acc[(rb)*4+f][(cb)*2+1] = __builtin_amdgcn_mfma_f32_16x16x32_bf16(     \
          aF[f][0], BV[1][0], acc[(rb)*4+f][(cb)*2+1], 0, 0, 0);             \
      acc[(rb)*4+f][(cb)*2+0] = __builtin_amdgcn_mfma_f32_16x16x32_bf16(     \
          aF[f][1], BV[0][1], acc[(rb)*4+f][(cb)*2+0], 0, 0, 0);             \
      acc[(rb)*4+f][(cb)*2+1] = __builtin_amdgcn_mfma_f32_16x16x32_bf16(     \
          aF[f][1], BV[1][1], acc[(rb)*4+f][(cb)*2+1], 0, 0, 0);             \
    } }

__global__ __launch_bounds__(512) void gemm8(
    const unsigned short* __restrict__ A, const unsigned short* __restrict__ Bt,
    float* __restrict__ C, int K, int lda, int ldb, int ldc,
    int Nreal, int NBmax,
    const float* __restrict__ bias, const float* __restrict__ resid,
    long strideB, long strideC,
    int gmode, unsigned short* __restrict__ Hp, const float* __restrict__ upb)
{
  // 128 KiB static LDS (gfx950 workgroup limit is 160 KiB)
  __shared__ __attribute__((aligned(1024))) char smem[131072];
  char* ldsA = smem;            // 2 x 32768 B
  char* ldsB = smem + 65536;    // 2 x 32768 B

  Bt += (long)blockIdx.z * strideB;
  C  += (long)blockIdx.z * strideC;

  const int tid  = threadIdx.x;
  const int lane = tid & 63, wvu = tid >> 6;
  const int wm = wvu >> 2, wn = wvu & 3;        // 2M x 4N waves
  const int m16 = lane & 15, qd = lane >> 4;

  // T1: bijective XCD swizzle on the 2D grid (z untouched)
  int nwg = gridDim.x * gridDim.y;
  int lin = blockIdx.y * gridDim.x + blockIdx.x;
  int qq_ = nwg >> 3, rr_ = nwg & 7, xcd = lin & 7, idx8 = lin >> 3;
  int swz = (xcd < rr_ ? xcd * (qq_ + 1) : rr_ * (qq_ + 1) + (xcd - rr_) * qq_) + idx8;
  int bx = swz % gridDim.x, by = swz / gridDim.x;
  const int n0 = bx * 256, m0 = by * 256;

  // ---- staging source pointers (per lane, pre-swizzled global column) ----
  const int l8 = lane >> 3, l7 = lane & 7;
  const int scol = ((l7 ^ l8) << 3);            // inverse-swizzled col (elems)
  const unsigned short *pA[2][2], *pB[2][2];
#pragma unroll
  for (int h = 0; h < 2; ++h)
#pragma unroll
    for (int k2 = 0; k2 < 2; ++k2) {
      int row = m0 + k2 * 128 + h * 64 + wvu * 8 + l8;
      pA[h][k2] = A + (long)row * lda + scol;
    }
#pragma unroll
  for (int cb = 0; cb < 2; ++cb)
#pragma unroll
    for (int i = 0; i < 2; ++i) {
      int qq = i * 64 + wvu * 8 + l8;                 // rho within chunk pair
      int n  = ((qq >> 5) << 6) + cb * 32 + (qq & 31);
      int gr = n0 + n; if (gr > NBmax - 1) gr = NBmax - 1;   // clamp
      pB[cb][i] = Bt + (long)gr * ldb + scol;
    }

  // swizzled ds_read slot offsets (bytes within a 128B LDS row)
  const int s0 = ((qd ^ (m16 & 7)) << 4);
  const int s1 = s0 ^ 64;                       // logical slot qd+4, swizzled

  f32x4 acc[8][4] = {};
  bf16x8 aF[4][2], b0v[2][2], b1v[2][2];

  const int NT = K >> 6;
  const int tp = (NT > 1) ? 1 : 0;

  // ---- prologue: stage T0 (buf0) and T1 (buf1) fully; keep T1 in flight
  STAGE_A(0,0,0,0); STAGE_A(0,1,0,0);
  STAGE_B(0,0,0,0); STAGE_B(0,1,0,0);
  STAGE_B(1,0,0,0); STAGE_B(1,1,0,0);
  STAGE_A(1,0,0,0); STAGE_A(1,1,0,0);
  STAGE_A(0,0,32768,tp); STAGE_A(0,1,32768,tp);
  STAGE_B(0,0,32768,tp); STAGE_B(0,1,32768,tp);
  STAGE_B(1,0,32768,tp); STAGE_B(1,1,32768,tp);
  STAGE_A(1,0,32768,tp); STAGE_A(1,1,32768,tp);
  asm volatile("s_waitcnt vmcnt(8)" ::: "memory");
  __builtin_amdgcn_s_barrier();
  __builtin_amdgcn_sched_barrier(0);

  for (int t = 0; t < NT; ++t) {
    const int co = (t & 1) << 15;
    const int t2 = (t + 2 < NT) ? t + 2 : NT - 1;
    // ---- phase 1: quadrant rb0 x cb0
    LOAD_A(0, co);
    LOAD_B(0, b0v, co);
    P_PRE(); MFMA_PH(0,0,b0v); P_POST();
    // ---- phase 2: quadrant rb0 x cb1   (A-rb0 dead -> stage t+2 A0)
    LOAD_B(1, b1v, co);
    STAGE_A(0,0,co,t2); STAGE_A(0,1,co,t2);
    P_PRE(); MFMA_PH(0,1,b1v); P_POST();
    // ---- phase 3: quadrant rb1 x cb1   (B regions dead -> stage t+2 B)
    LOAD_A(1, co);
    STAGE_B(0,0,co,t2); STAGE_B(0,1,co,t2);
    STAGE_B(1,0,co,t2); STAGE_B(1,1,co,t2);
    P_PRE(); MFMA_PH(1,1,b1v); P_POST();
    // ---- phase 4: quadrant rb1 x cb0   (A-rb1 dead -> stage t+2 A1)
    STAGE_A(1,0,co,t2); STAGE_A(1,1,co,t2);
    asm volatile("s_waitcnt vmcnt(8)" ::: "memory");
    P_PRE(); MFMA_PH(1,0,b0v); P_POST();
  }
  // drain outstanding LDS-DMA before epilogue / endpgm
  asm volatile("s_waitcnt vmcnt(0)" ::: "memory");

  // ---- epilogue ----
  if (gmode == 0) {
#pragma unroll
    for (int mf = 0; mf < 8; ++mf) {
      int gm = m0 + wm * 128 + mf * 16 + qd * 4;
#pragma unroll
      for (int nf = 0; nf < 4; ++nf) {
        int gn = n0 + wn * 64 + nf * 16 + m16;
        if (gn < Nreal) {
          float badd = bias ? bias[gn] : 0.f;
#pragma unroll
          for (int r = 0; r < 4; ++r) {
            float v = acc[mf][nf][r] + badd;
            if (resid) v += resid[(long)(gm + r) * ldc + gn];
            C[(long)(gm + r) * ldc + gn] = v;
          }
        }
      }
    }
  } else {
    // fused o1*gelu(o2) -> Hg bf16 (pair-interleaved B layout).
    // pair pp: o1 = acc[mf][2pp], o2 = acc[mf][2pp+1]; same lane, same rows.
    const int pbase = ((n0 + wn * 64) >> 5) * 16 + m16;
#pragma unroll
    for (int pp = 0; pp < 2; ++pp) {
      int p = pbase + pp * 16;
      bool valid = p < PROJ_N;
      float b1 = valid ? upb[p] : 0.f;
      float b2 = valid ? upb[PROJ_N + p] : 0.f;
#pragma unroll
      for (int mf = 0; mf < 8; ++mf) {
        int gm = m0 + wm * 128 + mf * 16 + qd * 4;
#pragma unroll
        for (int r = 0; r < 4; ++r) {
          float o1 = acc[mf][2*pp][r] + b1;
          float o2 = acc[mf][2*pp+1][r] + b2;
          float tt = o2 + 0.044715f * o2 * o2 * o2;
          float g = 0.5f * o2 * (1.f + tanhf(0.7978845608028654f * tt));
          unsigned short hw = valid ? f2bf(o1 * g) : (unsigned short)0;
          Hp[(long)(gm + r) * PROJ_PAD + p] = hw;
        }
      }
    }
  }
}

// ---------------------------------------------------------------------------
// Kernel 4: fused pointwise sLSTM + GroupNorm.  One block per row b;
// thread t owns j = 8t..8t+7 (all in GN group t&15, same recurrence slice).
// ---------------------------------------------------------------------------
__global__ __launch_bounds__(256) void slstm_gn(
    const float* __restrict__ g_i, const float* __restrict__ g_f,
    const float* __restrict__ g_z, const float* __restrict__ g_o,
    const float* __restrict__ Wib, const float* __restrict__ Wfb,
    const float* __restrict__ Wzb, const float* __restrict__ Wob,
    const float* __restrict__ Ri, const float* __restrict__ Rf,
    const float* __restrict__ Rz, const float* __restrict__ Ro,
    const float* __restrict__ Rib, const float* __restrict__ Rfb,
    const float* __restrict__ Rzb, const float* __restrict__ Rob,
    const float* __restrict__ c_in, const float* __restrict__ n_in,
    const float* __restrict__ h_in, const float* __restrict__ m_in,
    const int* __restrict__ flags,
    const float* __restrict__ gn_scale, const float* __restrict__ gn_bias,
    float* __restrict__ c_out, float* __restrict__ n_out,
    float* __restrict__ h_out, float* __restrict__ m_out,
    unsigned short* __restrict__ outn)
{
  int b = blockIdx.x, t = threadIdx.x;
  long base = ((long)b << 11) + t * 8;
  int nb = t & 15, hh = t >> 4;
  const float* hp = h_in + ((long)b << 11) + hh * 128 + nb * 8;
  float hv[8];
  {
    float4 a = *(const float4*)hp, c2 = *(const float4*)(hp + 4);
    hv[0]=a.x; hv[1]=a.y; hv[2]=a.z; hv[3]=a.w; hv[4]=c2.x; hv[5]=c2.y; hv[6]=c2.z; hv[7]=c2.w;
  }
  int fl = flags[b];
  int rb0 = nb * 64;
  float recI[8], recF[8], recZ[8], recO[8];
#pragma unroll
  for (int e = 0; e < 8; ++e) {
    float ri = Rib[nb*8+e], rf = Rfb[nb*8+e], rz = Rzb[nb*8+e], ro = Rob[nb*8+e];
#pragma unroll
    for (int d = 0; d < 8; ++d) {
      float h = hv[d];
      ri += h * Ri[rb0 + d*8 + e];
      rf += h * Rf[rb0 + d*8 + e];
      rz += h * Rz[rb0 + d*8 + e];
      ro += h * Ro[rb0 + d*8 + e];
    }
    recI[e] = ri; recF[e] = rf; recZ[e] = rz; recO[e] = ro;
  }
  float gi[8], gf[8], gz[8], go[8], ci[8], ni[8], mi[8];
#define LD8(dst, src) { float4 a_ = *(const float4*)((src)); float4 b_ = *(const float4*)((src) + 4); \
    dst[0]=a_.x; dst[1]=a_.y; dst[2]=a_.z; dst[3]=a_.w; dst[4]=b_.x; dst[5]=b_.y; dst[6]=b_.z; dst[7]=b_.w; }
  LD8(gi, g_i + base); LD8(gf, g_f + base); LD8(gz, g_z + base); LD8(go, g_o + base);
  LD8(ci, c_in + base); LD8(ni, n_in + base); LD8(mi, m_in + base);
  float wi[8], wf[8], wz[8], wo[8];
  LD8(wi, Wib + t*8); LD8(wf, Wfb + t*8); LD8(wz, Wzb + t*8); LD8(wo, Wob + t*8);
#undef LD8
  float ht[8], co_[8], no_[8], mo_[8];
  float s = 0.f, sq = 0.f;
#pragma unroll
  for (int e = 0; e < 8; ++e) {
    float iraw = gi[e] + wi[e] + recI[e];
    float fraw = gf[e] + wf[e] + recF[e];
    float zraw = gz[e] + wz[e] + recZ[e];
    float oraw = go[e] + wo[e] + recO[e];
    float ls = fminf(fraw, 0.f) - log1pf(expf(-fabsf(fraw)));
    float lfpm = mi[e] + ls;
    float mt = fl ? iraw : fmaxf(iraw, lfpm);
    float ot = 1.f / (1.f + expf(-oraw));
    float it = expf(iraw - mt);
    float ft = expf(lfpm - mt);
    float zt = tanhf(zraw);
    float ct = ft * ci[e] + it * zt;
    float nt = ft * ni[e] + it;
    float h = ot * ct / (nt + 1e-8f);
    ht[e] = h; co_[e] = ct; no_[e] = nt; mo_[e] = mt;
    s += h; sq += h * h;
  }
  __shared__ float s1[256], s2[256];
  s1[t] = s; s2[t] = sq;
  __syncthreads();
  for (int st = 128; st >= 16; st >>= 1) {
    if (t < st) { s1[t] += s1[t + st]; s2[t] += s2[t + st]; }
    __syncthreads();
  }
  float mu  = s1[nb] * (1.f / 128.f);
  float var = s2[nb] * (1.f / 128.f) - mu * mu;
  float rs  = rsqrtf(var + 1e-6f);
#define ST8(dst, src) { *(float4*)(dst) = make_float4(src[0],src[1],src[2],src[3]); \
    *(float4*)((dst)+4) = make_float4(src[4],src[5],src[6],src[7]); }
  ST8(c_out + base, co_); ST8(n_out + base, no_);
  ST8(h_out + base, ht);  ST8(m_out + base, mo_);
#undef ST8
  unsigned short ob[8];
#pragma unroll
  for (int e = 0; e < 8; ++e) {
    int dd = (t * 8 + e) & 127;
    ob[e] = f2bf((ht[e] - mu) * rs * gn_scale[dd] + gn_bias[dd]);
  }
  *(uint4*)&outn[base] = *(uint4*)ob;
}

// ---------------------------------------------------------------------------
extern "C" void kernel_launch(void* const* d_in, const int* in_sizes, int n_in,
                              void* d_out, int out_size, void* d_ws, size_t ws_size,
                              hipStream_t stream)
{
  const float* inputs  = (const float*)d_in[0];
  const float* c_in    = (const float*)d_in[1];
  const float* n_st    = (const float*)d_in[2];
  const float* h_in    = (const float*)d_in[3];
  const float* m_in    = (const float*)d_in[4];
  const float* x_prev  = (const float*)d_in[5];
  const float* ln_s    = (const float*)d_in[6];
  const float* ln_b    = (const float*)d_in[7];
  const float* Wz = (const float*)d_in[8];  const float* Wzb = (const float*)d_in[9];
  const float* Rz = (const float*)d_in[10]; const float* Rzb = (const float*)d_in[11];
  const float* Wi = (const float*)d_in[12]; const float* Wib = (const float*)d_in[13];
  const float* Ri = (const float*)d_in[14]; const float* Rib = (const float*)d_in[15];
  const float* Wf = (const float*)d_in[16]; const float* Wfb = (const float*)d_in[17];
  const float* Rf = (const float*)d_in[18]; const float* Rfb = (const float*)d_in[19];
  const float* Wo = (const float*)d_in[20]; const float* Wob = (const float*)d_in[21];
  const float* Ro = (const float*)d_in[22]; const float* Rob = (const float*)d_in[23];
  const float* gn_s = (const float*)d_in[24]; const float* gn_b = (const float*)d_in[25];
  const float* up_k = (const float*)d_in[26]; const float* up_b = (const float*)d_in[27];
  const float* dn_k = (const float*)d_in[28]; const float* dn_b = (const float*)d_in[29];

  // Workspace layout (lifetime-aliased):
  char* ws = (char*)d_ws;
  float* g_raw = (float*)ws;                                     // 4 x 33.55MB @ 0
  unsigned short* x_t_bf = (unsigned short*)(ws + 134217728);    // 16.78MB
  unsigned short* outn_bf = x_t_bf;                              // alias (after gates)
  unsigned short* Wt  = (unsigned short*)(ws + 150994944);       // 4 x 8.39MB
  unsigned short* upT = (unsigned short*)(ws + 184549376);       // 23.07MB (5632x2048)
  unsigned short* Hg  = (unsigned short*)(ws + 207618048);       // 23.07MB (4096x2816)
  unsigned short* dkT = (unsigned short*)(ws + 230686720);       // 11.53MB (2048x2816)
  int* flags = (int*)(ws + 242221056);                           // 16KB

  float* out   = (float*)d_out;
  float* out_c = out + (long)1 * 8388608;
  float* out_n = out + (long)2 * 8388608;
  float* out_h = out + (long)3 * 8388608;
  float* out_m = out + (long)4 * 8388608;
  float* out_xp = out + (long)5 * 8388608;

  // 1. LN + x_prev shift + flags
  ln_prep<<<BB, 256, 0, stream>>>(inputs, x_prev, n_st, ln_s, ln_b, x_t_bf, out_xp, flags);

  // 2. transpose-casts (gate order i,f,z,o); up_k uses pair-interleave
  transpose_cast<<<dim3(64, 64), 256, 0, stream>>>(Wi, Wt + 0L * 4194304, 2048, 2048, 2048, 2048);
  transpose_cast<<<dim3(64, 64), 256, 0, stream>>>(Wf, Wt + 1L * 4194304, 2048, 2048, 2048, 2048);
  transpose_cast<<<dim3(64, 64), 256, 0, stream>>>(Wz, Wt + 2L * 4194304, 2048, 2048, 2048, 2048);
  transpose_cast<<<dim3(64, 64), 256, 0, stream>>>(Wo, Wt + 3L * 4194304, 2048, 2048, 2048, 2048);
  transpose_cast_pair<<<dim3(64, 171), 256, 0, stream>>>(up_k, upT);
  transpose_cast<<<dim3(88, 64), 256, 0, stream>>>(dn_k, dkT, PROJ_N, 2048, 2048, PROJ_PAD);

  // 3. gate GEMMs: x_t(4096x2048) @ W^T -> g_raw[4]   (grid 8x16x4, 512thr)
  gemm8<<<dim3(8, 16, 4), 512, 0, stream>>>(x_t_bf, Wt, g_raw,
      2048, 2048, 2048, 2048, 2048, 2048, nullptr, nullptr, 4194304L, 8388608L,
      0, nullptr, nullptr);

  // 4. fused pointwise sLSTM + GroupNorm -> states + outn bf16
  slstm_gn<<<BB, 256, 0, stream>>>(
      g_raw, g_raw + 8388608L, g_raw + 2L * 8388608, g_raw + 3L * 8388608,
      Wib, Wfb, Wzb, Wob, Ri, Rf, Rz, Ro, Rib, Rfb, Rzb, Rob,
      c_in, n_st, h_in, m_in, flags, gn_s, gn_b,
      out_c, out_n, out_h, out_m, outn_bf);

  // 5. up GEMM (pair layout) + fused bias/gelu epilogue -> Hg bf16 (4096x2816)
  gemm8<<<dim3(UPN_PAIR / 256, 16, 1), 512, 0, stream>>>(outn_bf, upT, nullptr,
      2048, 2048, 2048, 0, UPN_PAIR, UPN_PAIR, nullptr, nullptr, 0L, 0L,
      1, Hg, up_b);

  // 6. down GEMM + bias + residual -> out (K=2816 -> NT=44)
  gemm8<<<dim3(8, 16, 1), 512, 0, stream>>>(Hg, dkT, out,
      PROJ_PAD, PROJ_PAD, PROJ_PAD, 2048, 2048, 2048, dn_b, inputs, 0L, 0L,
      0, nullptr, nullptr);
}